// Round 1
// baseline (12355.347 us; speedup 1.0000x reference)
//
#include <hip/hip_runtime.h>
#include <math.h>

#define EMBED   768
#define HEADS   12
#define HD      64
#define DEPTH   12
#define TOKS    32          // tokens per side
#define NTOK    1024        // 32*32
#define WINSZ   14
#define NWIN    9           // 3x3 windows (pad 32 -> 42)
#define WTOK    1764        // 9 * 196
#define WN      196         // 14*14
#define MLPDIM  3072
#define OUTC    256
#define LNEPS   1e-6f

// ---------------- generic GEMM: C[M,N] = A[M,K] @ B[N,K]^T + bias[N] -------
// requires N % 64 == 0, K % 16 == 0; M arbitrary (guarded)
__global__ __launch_bounds__(256) void gemm_abt(
        const float* __restrict__ A, const float* __restrict__ B,
        const float* __restrict__ bias, float* __restrict__ C,
        int M, int N, int K) {
    __shared__ float As[64][17];
    __shared__ float Bs[64][17];
    int tid = threadIdx.x;
    int tx = tid & 15, ty = tid >> 4;
    int n0 = blockIdx.x * 64;
    int m0 = blockIdx.y * 64;
    int lrow = tid >> 2;        // 0..63
    int lseg = (tid & 3) * 4;   // 0,4,8,12
    float acc[4][4];
#pragma unroll
    for (int i = 0; i < 4; i++)
#pragma unroll
        for (int j = 0; j < 4; j++) acc[i][j] = 0.f;

    for (int k0 = 0; k0 < K; k0 += 16) {
        float4 av = make_float4(0.f, 0.f, 0.f, 0.f);
        int am = m0 + lrow;
        if (am < M) av = *(const float4*)(A + (size_t)am * K + k0 + lseg);
        As[lrow][lseg + 0] = av.x; As[lrow][lseg + 1] = av.y;
        As[lrow][lseg + 2] = av.z; As[lrow][lseg + 3] = av.w;
        float4 bv = *(const float4*)(B + (size_t)(n0 + lrow) * K + k0 + lseg);
        Bs[lrow][lseg + 0] = bv.x; Bs[lrow][lseg + 1] = bv.y;
        Bs[lrow][lseg + 2] = bv.z; Bs[lrow][lseg + 3] = bv.w;
        __syncthreads();
#pragma unroll
        for (int kk = 0; kk < 16; kk++) {
            float a[4], b[4];
#pragma unroll
            for (int i = 0; i < 4; i++) a[i] = As[ty * 4 + i][kk];
#pragma unroll
            for (int j = 0; j < 4; j++) b[j] = Bs[tx * 4 + j][kk];
#pragma unroll
            for (int i = 0; i < 4; i++)
#pragma unroll
                for (int j = 0; j < 4; j++) acc[i][j] += a[i] * b[j];
        }
        __syncthreads();
    }
#pragma unroll
    for (int i = 0; i < 4; i++) {
        int m = m0 + ty * 4 + i;
        if (m >= M) break;
#pragma unroll
        for (int j = 0; j < 4; j++) {
            int n = n0 + tx * 4 + j;
            float v = acc[i][j];
            if (bias) v += bias[n];
            C[(size_t)m * N + n] = v;
        }
    }
}

// ---------------- LayerNorm over last dim ---------------------------------
// one block per row; out index transposed (c*M+row) if transpose!=0
__global__ __launch_bounds__(256) void ln_kernel(
        const float* __restrict__ in, const float* __restrict__ w,
        const float* __restrict__ b, float* __restrict__ out,
        int C, int transpose, int M) {
    int row = blockIdx.x;
    const float* x = in + (size_t)row * C;
    float s1 = 0.f, s2 = 0.f;
    for (int c = threadIdx.x; c < C; c += blockDim.x) {
        float v = x[c]; s1 += v; s2 += v * v;
    }
    for (int off = 32; off; off >>= 1) {
        s1 += __shfl_down(s1, off);
        s2 += __shfl_down(s2, off);
    }
    __shared__ float sh1[4], sh2[4];
    __shared__ float mu, rstd;
    int wave = threadIdx.x >> 6, lane = threadIdx.x & 63;
    if (lane == 0) { sh1[wave] = s1; sh2[wave] = s2; }
    __syncthreads();
    if (threadIdx.x == 0) {
        float t1 = 0.f, t2 = 0.f;
        int nw = blockDim.x >> 6;
        for (int i = 0; i < nw; i++) { t1 += sh1[i]; t2 += sh2[i]; }
        float m = t1 / C;
        float var = t2 / C - m * m;
        mu = m; rstd = rsqrtf(var + LNEPS);
    }
    __syncthreads();
    float m = mu, r = rstd;
    for (int c = threadIdx.x; c < C; c += blockDim.x) {
        float v = (x[c] - m) * r * w[c] + b[c];
        if (transpose) out[(size_t)c * M + row] = v;
        else           out[(size_t)row * C + c] = v;
    }
}

// ---------------- attention (one wave per (b, q-row)) ---------------------
// qkv rows: token-major, 2304 wide: [q(12x64) | k(12x64) | v(12x64)]
// blockIdx.y = win*HEADS + head ; blockIdx.x = q in [0,N)
__global__ __launch_bounds__(64) void attn_kernel(
        const float* __restrict__ qkv, const float* __restrict__ rel_h,
        const float* __restrict__ rel_w, float* __restrict__ out,
        int N, int H, int W) {
    __shared__ float qv[64];
    __shared__ float sc[1024];
    __shared__ float bh[32], bw[32];
    int b = blockIdx.y;
    int winI = b / HEADS, head = b % HEADS;
    int base = winI * N;
    int q = blockIdx.x;
    int lane = threadIdx.x;
    const float* qptr = qkv + (size_t)(base + q) * 2304 + head * 64;
    qv[lane] = qptr[lane];
    __syncthreads();
    int qh = q / W, qw = q % W;
    // decomposed rel-pos bias: bh[kh] = q . rel_h[qh-kh+H-1], bw[kw] likewise
    for (int t = lane; t < H + W; t += 64) {
        const float* r = (t < H) ? (rel_h + (size_t)(qh - t + H - 1) * 64)
                                 : (rel_w + (size_t)(qw - (t - H) + W - 1) * 64);
        float s = 0.f;
        for (int d = 0; d < 64; d++) s += qv[d] * r[d];
        if (t < H) bh[t] = s; else bw[t - H] = s;
    }
    __syncthreads();
    const float scale = 0.125f;   // 64^-0.5
    float lmax = -1e30f;
    for (int k = lane; k < N; k += 64) {
        const float* kp = qkv + (size_t)(base + k) * 2304 + 768 + head * 64;
        float s = 0.f;
        for (int d = 0; d < 64; d++) s += qv[d] * kp[d];
        s = s * scale + bh[k / W] + bw[k % W];
        sc[k] = s;
        lmax = fmaxf(lmax, s);
    }
    for (int off = 32; off; off >>= 1) lmax = fmaxf(lmax, __shfl_xor(lmax, off));
    __syncthreads();
    float lsum = 0.f;
    for (int k = lane; k < N; k += 64) {
        float e = expf(sc[k] - lmax);
        sc[k] = e;
        lsum += e;
    }
    for (int off = 32; off; off >>= 1) lsum += __shfl_xor(lsum, off);
    __syncthreads();
    float inv = 1.f / lsum;
    float acc = 0.f;
    for (int k = 0; k < N; k++) {
        const float* vp = qkv + (size_t)(base + k) * 2304 + 1536 + head * 64;
        acc += sc[k] * vp[lane];
    }
    out[(size_t)(base + q) * EMBED + head * 64 + lane] = acc * inv;
}

// ---------------- window partition / unpartition --------------------------
__global__ __launch_bounds__(256) void win_partition(
        const float* __restrict__ in, float* __restrict__ out) {
    int t = blockIdx.x;                    // 0..1763
    int w = t / WN, r = t % WN;
    int wy = r / WINSZ, wx = r % WINSZ;
    int gy = (w / 3) * WINSZ + wy, gx = (w % 3) * WINSZ + wx;
    bool valid = (gy < TOKS && gx < TOKS);
    const float* src = in + (size_t)(gy * TOKS + gx) * EMBED;
    float* dst = out + (size_t)t * EMBED;
    for (int c = threadIdx.x; c < EMBED; c += blockDim.x)
        dst[c] = valid ? src[c] : 0.f;
}

__global__ __launch_bounds__(256) void win_unpartition_add(
        const float* __restrict__ winb, float* __restrict__ h) {
    int p = blockIdx.x;                    // 0..1023
    int gy = p / TOKS, gx = p % TOKS;
    int w = (gy / WINSZ) * 3 + gx / WINSZ;
    int t = w * WN + (gy % WINSZ) * WINSZ + (gx % WINSZ);
    const float* src = winb + (size_t)t * EMBED;
    float* dst = h + (size_t)p * EMBED;
    for (int c = threadIdx.x; c < EMBED; c += blockDim.x) dst[c] += src[c];
}

// ---------------- elementwise helpers -------------------------------------
__global__ void add_inplace(float* __restrict__ a, const float* __restrict__ b, int n) {
    int i = blockIdx.x * blockDim.x + threadIdx.x;
    if (i < n) a[i] += b[i];
}
__global__ void gelu_kernel(float* __restrict__ x, int n) {
    int i = blockIdx.x * blockDim.x + threadIdx.x;
    if (i < n) {
        float v = x[i];
        x[i] = 0.5f * v * (1.f + erff(v * 0.70710678118654752f));
    }
}
__global__ void add_bias_pos(float* __restrict__ h, const float* __restrict__ pb,
                             const float* __restrict__ pos, int n) {
    int i = blockIdx.x * blockDim.x + threadIdx.x;
    if (i < n) h[i] += pb[i % EMBED] + pos[i];
}

// ---------------- patch-embed im2col --------------------------------------
__global__ void im2col_patch(const float* __restrict__ x, float* __restrict__ A, int n) {
    int i = blockIdx.x * blockDim.x + threadIdx.x;
    if (i >= n) return;
    int t = i / EMBED, kidx = i % EMBED;
    int c = kidx >> 8, r = kidx & 255;
    int ph = r >> 4, pw = r & 15;
    int ty = t >> 5, tx = t & 31;
    A[i] = x[(size_t)c * 512 * 512 + (size_t)(ty * 16 + ph) * 512 + (tx * 16 + pw)];
}

// ---------------- neck 3x3 conv (NHWC in/out, bias-free, SAME) ------------
__global__ __launch_bounds__(256) void conv3x3(
        const float* __restrict__ in, const float* __restrict__ w,
        float* __restrict__ out) {
    int p = blockIdx.x;
    int py = p / TOKS, px = p % TOKS;
    int o = threadIdx.x;
    float acc = 0.f;
    for (int ky = 0; ky < 3; ky++) {
        int ny = py + ky - 1;
        if (ny < 0 || ny >= TOKS) continue;
        for (int kx = 0; kx < 3; kx++) {
            int nx = px + kx - 1;
            if (nx < 0 || nx >= TOKS) continue;
            const float* ip = in + (size_t)(ny * TOKS + nx) * OUTC;
            const float* wp = w + (size_t)o * OUTC * 9 + ky * 3 + kx;
            for (int c = 0; c < OUTC; c++) acc += ip[c] * wp[c * 9];
        }
    }
    out[(size_t)p * OUTC + o] = acc;
}

// ---------------- host orchestration --------------------------------------
extern "C" void kernel_launch(void* const* d_in, const int* in_sizes, int n_in,
                              void* d_out, int out_size, void* d_ws, size_t ws_size,
                              hipStream_t stream) {
    const float* x        = (const float*)d_in[0];
    const float* patch_w  = (const float*)d_in[1];
    const float* patch_b  = (const float*)d_in[2];
    const float* pos      = (const float*)d_in[3];
    const float* qkv_w    = (const float*)d_in[4];
    const float* qkv_b    = (const float*)d_in[5];
    const float* proj_w   = (const float*)d_in[6];
    const float* proj_b   = (const float*)d_in[7];
    const float* n1w      = (const float*)d_in[8];
    const float* n1b      = (const float*)d_in[9];
    const float* n2w      = (const float*)d_in[10];
    const float* n2b      = (const float*)d_in[11];
    const float* mlp_w1   = (const float*)d_in[12];
    const float* mlp_b1   = (const float*)d_in[13];
    const float* mlp_w2   = (const float*)d_in[14];
    const float* mlp_b2   = (const float*)d_in[15];
    const float* rhw      = (const float*)d_in[16];
    const float* rww      = (const float*)d_in[17];
    const float* rhg      = (const float*)d_in[18];
    const float* rwg      = (const float*)d_in[19];
    const float* neck_w1  = (const float*)d_in[20];
    const float* nl1w     = (const float*)d_in[21];
    const float* nl1b     = (const float*)d_in[22];
    const float* neck_w2  = (const float*)d_in[23];
    const float* nl2w     = (const float*)d_in[24];
    const float* nl2b     = (const float*)d_in[25];

    float* ws  = (float*)d_ws;
    float* H   = ws;                        // 1024*768
    float* XW  = H   + (size_t)NTOK * EMBED;    // 1764*768
    float* QKV = XW  + (size_t)WTOK * EMBED;    // 1764*2304 (also MLP mid 1024*3072)
    float* AO  = QKV + (size_t)WTOK * 3 * EMBED;// 1764*768
    float* PO  = AO  + (size_t)WTOK * EMBED;    // 1764*768
    float* LNF = PO  + (size_t)WTOK * EMBED;    // 1024*768

    const int NE = NTOK * EMBED;            // 786432

    // ---- patch embed: im2col + GEMM + bias + pos ----
    im2col_patch<<<(NE + 255) / 256, 256, 0, stream>>>(x, XW, NE);
    gemm_abt<<<dim3(EMBED / 64, NTOK / 64), 256, 0, stream>>>(
        XW, patch_w, nullptr, H, NTOK, EMBED, EMBED);
    add_bias_pos<<<(NE + 255) / 256, 256, 0, stream>>>(H, patch_b, pos, NE);

    for (int i = 0; i < DEPTH; i++) {
        bool glob = (i == 2 || i == 5 || i == 8 || i == 11);
        // LN1
        ln_kernel<<<NTOK, 256, 0, stream>>>(H, n1w + i * EMBED, n1b + i * EMBED,
                                            LNF, EMBED, 0, NTOK);
        if (!glob) {
            win_partition<<<WTOK, 256, 0, stream>>>(LNF, XW);
            gemm_abt<<<dim3(3 * EMBED / 64, (WTOK + 63) / 64), 256, 0, stream>>>(
                XW, qkv_w + (size_t)i * 3 * EMBED * EMBED, qkv_b + i * 3 * EMBED,
                QKV, WTOK, 3 * EMBED, EMBED);
            attn_kernel<<<dim3(WN, NWIN * HEADS), 64, 0, stream>>>(
                QKV, rhw + (size_t)i * 27 * HD, rww + (size_t)i * 27 * HD,
                AO, WN, WINSZ, WINSZ);
            gemm_abt<<<dim3(EMBED / 64, (WTOK + 63) / 64), 256, 0, stream>>>(
                AO, proj_w + (size_t)i * EMBED * EMBED, proj_b + i * EMBED,
                PO, WTOK, EMBED, EMBED);
            win_unpartition_add<<<NTOK, 256, 0, stream>>>(PO, H);
        } else {
            gemm_abt<<<dim3(3 * EMBED / 64, NTOK / 64), 256, 0, stream>>>(
                LNF, qkv_w + (size_t)i * 3 * EMBED * EMBED, qkv_b + i * 3 * EMBED,
                QKV, NTOK, 3 * EMBED, EMBED);
            attn_kernel<<<dim3(NTOK, HEADS), 64, 0, stream>>>(
                QKV, rhg + (size_t)i * 63 * HD, rwg + (size_t)i * 63 * HD,
                AO, NTOK, TOKS, TOKS);
            gemm_abt<<<dim3(EMBED / 64, NTOK / 64), 256, 0, stream>>>(
                AO, proj_w + (size_t)i * EMBED * EMBED, proj_b + i * EMBED,
                PO, NTOK, EMBED, EMBED);
            add_inplace<<<(NE + 255) / 256, 256, 0, stream>>>(H, PO, NE);
        }
        // MLP
        ln_kernel<<<NTOK, 256, 0, stream>>>(H, n2w + i * EMBED, n2b + i * EMBED,
                                            LNF, EMBED, 0, NTOK);
        gemm_abt<<<dim3(MLPDIM / 64, NTOK / 64), 256, 0, stream>>>(
            LNF, mlp_w1 + (size_t)i * MLPDIM * EMBED, mlp_b1 + i * MLPDIM,
            QKV, NTOK, MLPDIM, EMBED);
        gelu_kernel<<<(NTOK * MLPDIM + 255) / 256, 256, 0, stream>>>(QKV, NTOK * MLPDIM);
        gemm_abt<<<dim3(EMBED / 64, NTOK / 64), 256, 0, stream>>>(
            QKV, mlp_w2 + (size_t)i * EMBED * MLPDIM, mlp_b2 + i * EMBED,
            AO, NTOK, EMBED, MLPDIM);
        add_inplace<<<(NE + 255) / 256, 256, 0, stream>>>(H, AO, NE);
    }

    // ---- neck ----
    gemm_abt<<<dim3(OUTC / 64, NTOK / 64), 256, 0, stream>>>(
        H, neck_w1, nullptr, XW, NTOK, OUTC, EMBED);
    ln_kernel<<<NTOK, 256, 0, stream>>>(XW, nl1w, nl1b, AO, OUTC, 0, NTOK);
    conv3x3<<<NTOK, 256, 0, stream>>>(AO, neck_w2, PO);
    ln_kernel<<<NTOK, 256, 0, stream>>>(PO, nl2w, nl2b, (float*)d_out, OUTC, 1, NTOK);
}

// Round 2
// 5768.861 us; speedup vs baseline: 2.1417x; 2.1417x over previous
//
#include <hip/hip_runtime.h>
#include <math.h>

#define EMBED   768
#define HEADS   12
#define DEPTH   12
#define TOKS    32
#define NTOK    1024
#define WINSZ   14
#define NWIN    9
#define WTOK    1764        // 9*196
#define WN      196
#define MLPDIM  3072
#define OUTC    256
#define LNEPS   1e-6f

typedef __attribute__((ext_vector_type(8))) short short8;
typedef __attribute__((ext_vector_type(4))) float float4v;

__device__ __forceinline__ unsigned short f2bf(float f) {
    unsigned u = __float_as_uint(f);
    unsigned r = (u + 0x7fffu + ((u >> 16) & 1u)) >> 16;
    return (unsigned short)r;
}

// ---------------- f32 -> bf16 conversion (4 elems/thread) ------------------
__global__ void f2b4(const float* __restrict__ in, unsigned short* __restrict__ out, int n4) {
    int i = blockIdx.x * blockDim.x + threadIdx.x;
    if (i >= n4) return;
    float4 v = ((const float4*)in)[i];
    ushort4 o;
    o.x = f2bf(v.x); o.y = f2bf(v.y); o.z = f2bf(v.z); o.w = f2bf(v.w);
    ((ushort4*)out)[i] = o;
}

// ---------------- bf16 MFMA GEMM: C[M,N] = A[M,K] @ B[N,K]^T + bias --------
// A,B bf16 row-major; requires N%128==0, K%64==0; M arbitrary (clamped/guarded)
template<bool GELU>
__global__ __launch_bounds__(256) void gemm_bf16(
        const unsigned short* __restrict__ A, const unsigned short* __restrict__ B,
        const float* __restrict__ bias, void* __restrict__ Cout,
        int M, int N, int K) {
    __shared__ unsigned short As[128 * 72];   // [128][64] + pad 8
    __shared__ unsigned short Bs[128 * 72];
    const int tid = threadIdx.x;
    const int lane = tid & 63, wave = tid >> 6;
    const int wm = wave >> 1, wn = wave & 1;
    const int m0 = blockIdx.y * 128, n0 = blockIdx.x * 128;
    float4v acc[4][4];
#pragma unroll
    for (int i = 0; i < 4; i++)
#pragma unroll
        for (int j = 0; j < 4; j++) acc[i][j] = (float4v){0.f, 0.f, 0.f, 0.f};

    const int lrow = tid >> 3;          // 0..31
    const int lcol = (tid & 7) * 8;     // 0..56 (bf16 elems)
    const int q4 = lane >> 4;           // quad id 0..3
    const int l15 = lane & 15;

    for (int k0 = 0; k0 < K; k0 += 64) {
        __syncthreads();
#pragma unroll
        for (int r = 0; r < 4; r++) {
            int row = lrow + r * 32;
            int gm = m0 + row; if (gm >= M) gm = M - 1;
            uint4 va = *(const uint4*)(A + (size_t)gm * K + k0 + lcol);
            *(uint4*)(&As[row * 72 + lcol]) = va;
            int gn = n0 + row;   // N % 128 == 0, always valid
            uint4 vb = *(const uint4*)(B + (size_t)gn * K + k0 + lcol);
            *(uint4*)(&Bs[row * 72 + lcol]) = vb;
        }
        __syncthreads();
#pragma unroll
        for (int kk = 0; kk < 64; kk += 32) {
            short8 af[4], bf[4];
#pragma unroll
            for (int i = 0; i < 4; i++)
                af[i] = *(const short8*)(&As[(wm * 64 + i * 16 + l15) * 72 + kk + q4 * 8]);
#pragma unroll
            for (int j = 0; j < 4; j++)
                bf[j] = *(const short8*)(&Bs[(wn * 64 + j * 16 + l15) * 72 + kk + q4 * 8]);
#pragma unroll
            for (int i = 0; i < 4; i++)
#pragma unroll
                for (int j = 0; j < 4; j++)
                    acc[i][j] = __builtin_amdgcn_mfma_f32_16x16x32_bf16(
                        af[i], bf[j], acc[i][j], 0, 0, 0);
        }
    }
#pragma unroll
    for (int i = 0; i < 4; i++) {
#pragma unroll
        for (int r = 0; r < 4; r++) {
            int m = m0 + wm * 64 + i * 16 + q4 * 4 + r;
            if (m >= M) continue;
#pragma unroll
            for (int j = 0; j < 4; j++) {
                int n = n0 + wn * 64 + j * 16 + l15;
                float v = acc[i][j][r];
                if (bias) v += bias[n];
                if (GELU) {
                    v = 0.5f * v * (1.f + erff(v * 0.70710678118654752f));
                    ((unsigned short*)Cout)[(size_t)m * N + n] = f2bf(v);
                } else {
                    ((float*)Cout)[(size_t)m * N + n] = v;
                }
            }
        }
    }
}

// ---------------- LayerNorm over last dim ----------------------------------
// mode 0: f32 out [M,C]; mode 1: bf16 out [M,C]; mode 2: f32 out transposed [C,M]
__global__ __launch_bounds__(256) void ln_kernel(
        const float* __restrict__ in, const float* __restrict__ w,
        const float* __restrict__ b, void* __restrict__ out,
        int C, int mode, int M) {
    int row = blockIdx.x;
    const float* x = in + (size_t)row * C;
    float s1 = 0.f, s2 = 0.f;
    for (int c = threadIdx.x; c < C; c += blockDim.x) {
        float v = x[c]; s1 += v; s2 += v * v;
    }
    for (int off = 32; off; off >>= 1) {
        s1 += __shfl_down(s1, off);
        s2 += __shfl_down(s2, off);
    }
    __shared__ float sh1[4], sh2[4];
    __shared__ float mu, rstd;
    int wave = threadIdx.x >> 6, lane = threadIdx.x & 63;
    if (lane == 0) { sh1[wave] = s1; sh2[wave] = s2; }
    __syncthreads();
    if (threadIdx.x == 0) {
        float t1 = 0.f, t2 = 0.f;
        for (int i = 0; i < 4; i++) { t1 += sh1[i]; t2 += sh2[i]; }
        float m = t1 / C;
        mu = m; rstd = rsqrtf(t2 / C - m * m + LNEPS);
    }
    __syncthreads();
    float m = mu, r = rstd;
    for (int c = threadIdx.x; c < C; c += blockDim.x) {
        float v = (x[c] - m) * r * w[c] + b[c];
        if (mode == 0)      ((float*)out)[(size_t)row * C + c] = v;
        else if (mode == 1) ((unsigned short*)out)[(size_t)row * C + c] = f2bf(v);
        else                ((float*)out)[(size_t)c * M + row] = v;
    }
}

// ---------------- attention: block = 4 waves = 4 q rows --------------------
// qkv f32 rows [tok][2304] = [q|k|v] x 12 heads x 64; out bf16 [tok][768]
template<int TN, int TH, int TW>
__global__ __launch_bounds__(256) void attn2(
        const float* __restrict__ qkv, const float* __restrict__ rel_h,
        const float* __restrict__ rel_w, unsigned short* __restrict__ out) {
    constexpr int NT = (TN + 63) / 64;
    __shared__ float Ks[64 * 65];
    __shared__ float Vs[64 * 65];
    __shared__ float sc[4][TN];
    __shared__ float qs[4][64];
    __shared__ float bhs[4][TH];
    __shared__ float bws[4][TW];
    const int tid = threadIdx.x;
    const int lane = tid & 63, w = tid >> 6;
    const int bh_ = blockIdx.y;
    const int winI = bh_ / HEADS, head = bh_ % HEADS;
    const int base = winI * TN;
    const int q = blockIdx.x * 4 + w;
    const int qh = q / TW, qw = q % TW;
    float qreg = qkv[(size_t)(base + q) * 2304 + head * 64 + lane];
    qs[w][lane] = qreg;
    // decomposed rel-pos bias (per-wave; no cross-wave deps)
    {
        int t = lane;
        bool valid = t < TH + TW;
        const float* rp = (t < TH) ? rel_h + (size_t)(qh - t + TH - 1) * 64
                        : valid    ? rel_w + (size_t)(qw - (t - TH) + TW - 1) * 64
                                   : rel_h;
        float s0 = 0.f, s1 = 0.f, s2 = 0.f, s3 = 0.f;
#pragma unroll
        for (int d = 0; d < 64; d += 4) {
            s0 += qs[w][d + 0] * rp[d + 0];
            s1 += qs[w][d + 1] * rp[d + 1];
            s2 += qs[w][d + 2] * rp[d + 2];
            s3 += qs[w][d + 3] * rp[d + 3];
        }
        float s = (s0 + s1) + (s2 + s3);
        if (t < TH) bhs[w][t] = s;
        else if (valid) bws[w][t - TH] = s;
    }
    // ---- score pass ----
    float lmax = -1e30f;
    for (int kt = 0; kt < NT; kt++) {
        __syncthreads();
#pragma unroll
        for (int r = 0; r < 4; r++) {
            int kl = (tid >> 4) + r * 16;
            int col = (tid & 15) * 4;
            int kg = kt * 64 + kl;
            float4 v = make_float4(0.f, 0.f, 0.f, 0.f);
            if (kg < TN)
                v = *(const float4*)(qkv + (size_t)(base + kg) * 2304 + 768 + head * 64 + col);
            Ks[kl * 65 + col + 0] = v.x; Ks[kl * 65 + col + 1] = v.y;
            Ks[kl * 65 + col + 2] = v.z; Ks[kl * 65 + col + 3] = v.w;
        }
        __syncthreads();
        int kg = kt * 64 + lane;
        float s0 = 0.f, s1 = 0.f, s2 = 0.f, s3 = 0.f;
#pragma unroll
        for (int d = 0; d < 64; d += 4) {
            s0 += qs[w][d + 0] * Ks[lane * 65 + d + 0];
            s1 += qs[w][d + 1] * Ks[lane * 65 + d + 1];
            s2 += qs[w][d + 2] * Ks[lane * 65 + d + 2];
            s3 += qs[w][d + 3] * Ks[lane * 65 + d + 3];
        }
        if (kg < TN) {
            float s = ((s0 + s1) + (s2 + s3)) * 0.125f + bhs[w][kg / TW] + bws[w][kg % TW];
            sc[w][kg] = s;
            lmax = fmaxf(lmax, s);
        }
    }
    for (int off = 32; off; off >>= 1) lmax = fmaxf(lmax, __shfl_xor(lmax, off));
    float lsum = 0.f;
    for (int k = lane; k < TN; k += 64) {
        float e = expf(sc[w][k] - lmax);
        sc[w][k] = e; lsum += e;
    }
    for (int off = 32; off; off >>= 1) lsum += __shfl_xor(lsum, off);
    float inv = 1.f / lsum;
    // ---- PV pass ----
    float a0 = 0.f, a1 = 0.f, a2 = 0.f, a3 = 0.f;
    for (int kt = 0; kt < NT; kt++) {
        __syncthreads();
#pragma unroll
        for (int r = 0; r < 4; r++) {
            int kl = (tid >> 4) + r * 16;
            int col = (tid & 15) * 4;
            int kg = kt * 64 + kl;
            float4 v = make_float4(0.f, 0.f, 0.f, 0.f);
            if (kg < TN)
                v = *(const float4*)(qkv + (size_t)(base + kg) * 2304 + 1536 + head * 64 + col);
            Vs[kl * 65 + col + 0] = v.x; Vs[kl * 65 + col + 1] = v.y;
            Vs[kl * 65 + col + 2] = v.z; Vs[kl * 65 + col + 3] = v.w;
        }
        __syncthreads();
        int kmax = TN - kt * 64; if (kmax > 64) kmax = 64;
        const float* scw = &sc[w][kt * 64];
        int kk = 0;
        for (; kk + 4 <= kmax; kk += 4) {
            a0 += scw[kk + 0] * Vs[(kk + 0) * 65 + lane];
            a1 += scw[kk + 1] * Vs[(kk + 1) * 65 + lane];
            a2 += scw[kk + 2] * Vs[(kk + 2) * 65 + lane];
            a3 += scw[kk + 3] * Vs[(kk + 3) * 65 + lane];
        }
        for (; kk < kmax; kk++) a0 += scw[kk] * Vs[kk * 65 + lane];
    }
    float acc = (a0 + a1) + (a2 + a3);
    out[(size_t)(base + q) * EMBED + head * 64 + lane] = f2bf(acc * inv);
}

// ---------------- window partition / unpartition ---------------------------
__global__ __launch_bounds__(256) void win_partition(
        const float* __restrict__ in, unsigned short* __restrict__ out) {
    int t = blockIdx.x;                    // 0..1763
    int w = t / WN, r = t % WN;
    int wy = r / WINSZ, wx = r % WINSZ;
    int gy = (w / 3) * WINSZ + wy, gx = (w % 3) * WINSZ + wx;
    bool valid = (gy < TOKS && gx < TOKS);
    const float* src = in + (size_t)(gy * TOKS + gx) * EMBED;
    unsigned short* dst = out + (size_t)t * EMBED;
    for (int c = threadIdx.x; c < EMBED; c += blockDim.x)
        dst[c] = valid ? f2bf(src[c]) : f2bf(0.f);
}

__global__ __launch_bounds__(256) void win_unpartition_add(
        const float* __restrict__ winb, float* __restrict__ h) {
    int p = blockIdx.x;                    // 0..1023
    int gy = p / TOKS, gx = p % TOKS;
    int w = (gy / WINSZ) * 3 + gx / WINSZ;
    int t = w * WN + (gy % WINSZ) * WINSZ + (gx % WINSZ);
    const float* src = winb + (size_t)t * EMBED;
    float* dst = h + (size_t)p * EMBED;
    for (int c = threadIdx.x; c < EMBED; c += blockDim.x) dst[c] += src[c];
}

// ---------------- elementwise ----------------------------------------------
__global__ void add_inplace(float* __restrict__ a, const float* __restrict__ b, int n) {
    int i = blockIdx.x * blockDim.x + threadIdx.x;
    if (i < n) a[i] += b[i];
}
__global__ void add_bias_pos(float* __restrict__ h, const float* __restrict__ pb,
                             const float* __restrict__ pos, int n) {
    int i = blockIdx.x * blockDim.x + threadIdx.x;
    if (i < n) h[i] += pb[i % EMBED] + pos[i];
}

// ---------------- patch-embed im2col (bf16 out) ----------------------------
__global__ void im2col_patch(const float* __restrict__ x, unsigned short* __restrict__ A, int n) {
    int i = blockIdx.x * blockDim.x + threadIdx.x;
    if (i >= n) return;
    int t = i / EMBED, kidx = i % EMBED;
    int c = kidx >> 8, r = kidx & 255;
    int ph = r >> 4, pw = r & 15;
    int ty = t >> 5, tx = t & 31;
    A[i] = f2bf(x[(size_t)c * 512 * 512 + (size_t)(ty * 16 + ph) * 512 + (tx * 16 + pw)]);
}

// ---------------- neck 3x3 conv im2col (bf16 out) --------------------------
// K index = c*9 + ky*3 + kx, matching neck_w2 [o][c][ky][kx] flat layout
__global__ void im2col3(const float* __restrict__ in, unsigned short* __restrict__ out, int n) {
    int i = blockIdx.x * blockDim.x + threadIdx.x;
    if (i >= n) return;
    int p = i / 2304, k = i % 2304;
    int c = k / 9, r9 = k % 9;
    int ky = r9 / 3, kx = r9 % 3;
    int py = p >> 5, px = p & 31;
    int ny = py + ky - 1, nx = px + kx - 1;
    float v = (ny >= 0 && ny < TOKS && nx >= 0 && nx < TOKS)
                ? in[(size_t)(ny * TOKS + nx) * OUTC + c] : 0.f;
    out[i] = f2bf(v);
}

// ---------------- host orchestration ---------------------------------------
extern "C" void kernel_launch(void* const* d_in, const int* in_sizes, int n_in,
                              void* d_out, int out_size, void* d_ws, size_t ws_size,
                              hipStream_t stream) {
    const float* x        = (const float*)d_in[0];
    const float* patch_w  = (const float*)d_in[1];
    const float* patch_b  = (const float*)d_in[2];
    const float* pos      = (const float*)d_in[3];
    const float* qkv_w    = (const float*)d_in[4];
    const float* qkv_b    = (const float*)d_in[5];
    const float* proj_w   = (const float*)d_in[6];
    const float* proj_b   = (const float*)d_in[7];
    const float* n1w      = (const float*)d_in[8];
    const float* n1b      = (const float*)d_in[9];
    const float* n2w      = (const float*)d_in[10];
    const float* n2b      = (const float*)d_in[11];
    const float* mlp_w1   = (const float*)d_in[12];
    const float* mlp_b1   = (const float*)d_in[13];
    const float* mlp_w2   = (const float*)d_in[14];
    const float* mlp_b2   = (const float*)d_in[15];
    const float* rhw      = (const float*)d_in[16];
    const float* rww      = (const float*)d_in[17];
    const float* rhg      = (const float*)d_in[18];
    const float* rwg      = (const float*)d_in[19];
    const float* neck_w1  = (const float*)d_in[20];
    const float* nl1w     = (const float*)d_in[21];
    const float* nl1b     = (const float*)d_in[22];
    const float* neck_w2  = (const float*)d_in[23];
    const float* nl2w     = (const float*)d_in[24];
    const float* nl2b     = (const float*)d_in[25];

    float* H    = (float*)d_ws;                 // 1024*768 f32
    float* QKV  = H + 786432;                   // 1764*2304 f32
    float* PO   = QKV + 4064256;                // 1764*768 f32
    float* LNF  = PO + 1354752;                 // 1764*768 f32
    unsigned short* XWb = (unsigned short*)(LNF + 1354752);  // 1764*768 bf16
    unsigned short* AOb = XWb + 1354752;        // 1764*768 bf16
    unsigned short* WQ  = AOb + 1354752;        // 2304*768 bf16
    unsigned short* WP  = WQ + 1769472;         // 768*768 bf16
    unsigned short* W1  = WP + 589824;          // 3072*768 bf16
    unsigned short* W2  = W1 + 2359296;         // 768*3072 bf16
    unsigned short* MIDB  = (unsigned short*)QKV;  // alias (mlp mid 1024*3072 bf16)
    unsigned short* CONVA = (unsigned short*)QKV;  // alias (neck im2col 1024*2304 bf16)

    const int NE = NTOK * EMBED;                // 786432

    // ---- patch embed ----
    im2col_patch<<<(NE + 255) / 256, 256, 0, stream>>>(x, XWb, NE);
    f2b4<<<(EMBED * EMBED / 4 + 255) / 256, 256, 0, stream>>>(patch_w, WQ, EMBED * EMBED / 4);
    gemm_bf16<false><<<dim3(EMBED / 128, NTOK / 128), 256, 0, stream>>>(
        XWb, WQ, nullptr, H, NTOK, EMBED, EMBED);
    add_bias_pos<<<(NE + 255) / 256, 256, 0, stream>>>(H, patch_b, pos, NE);

    for (int i = 0; i < DEPTH; i++) {
        bool glob = (i == 2 || i == 5 || i == 8 || i == 11);
        // convert this layer's weights to bf16
        f2b4<<<(2304 * 768 / 4 + 255) / 256, 256, 0, stream>>>(
            qkv_w + (size_t)i * 2304 * 768, WQ, 2304 * 768 / 4);
        f2b4<<<(768 * 768 / 4 + 255) / 256, 256, 0, stream>>>(
            proj_w + (size_t)i * 768 * 768, WP, 768 * 768 / 4);
        f2b4<<<(3072 * 768 / 4 + 255) / 256, 256, 0, stream>>>(
            mlp_w1 + (size_t)i * 3072 * 768, W1, 3072 * 768 / 4);
        f2b4<<<(768 * 3072 / 4 + 255) / 256, 256, 0, stream>>>(
            mlp_w2 + (size_t)i * 768 * 3072, W2, 768 * 3072 / 4);

        if (!glob) {
            ln_kernel<<<NTOK, 256, 0, stream>>>(H, n1w + i * EMBED, n1b + i * EMBED,
                                                LNF, EMBED, 0, NTOK);
            win_partition<<<WTOK, 256, 0, stream>>>(LNF, XWb);
            gemm_bf16<false><<<dim3(2304 / 128, (WTOK + 127) / 128), 256, 0, stream>>>(
                XWb, WQ, qkv_b + i * 2304, QKV, WTOK, 2304, EMBED);
            attn2<WN, WINSZ, WINSZ><<<dim3(WN / 4, NWIN * HEADS), 256, 0, stream>>>(
                QKV, rhw + (size_t)i * 27 * 64, rww + (size_t)i * 27 * 64, AOb);
            gemm_bf16<false><<<dim3(EMBED / 128, (WTOK + 127) / 128), 256, 0, stream>>>(
                AOb, WP, proj_b + i * EMBED, PO, WTOK, EMBED, EMBED);
            win_unpartition_add<<<NTOK, 256, 0, stream>>>(PO, H);
        } else {
            ln_kernel<<<NTOK, 256, 0, stream>>>(H, n1w + i * EMBED, n1b + i * EMBED,
                                                XWb, EMBED, 1, NTOK);
            gemm_bf16<false><<<dim3(2304 / 128, NTOK / 128), 256, 0, stream>>>(
                XWb, WQ, qkv_b + i * 2304, QKV, NTOK, 2304, EMBED);
            attn2<NTOK, TOKS, TOKS><<<dim3(NTOK / 4, HEADS), 256, 0, stream>>>(
                QKV, rhg + (size_t)i * 63 * 64, rwg + (size_t)i * 63 * 64, AOb);
            gemm_bf16<false><<<dim3(EMBED / 128, NTOK / 128), 256, 0, stream>>>(
                AOb, WP, proj_b + i * EMBED, PO, NTOK, EMBED, EMBED);
            add_inplace<<<(NE + 255) / 256, 256, 0, stream>>>(H, PO, NE);
        }
        // MLP
        ln_kernel<<<NTOK, 256, 0, stream>>>(H, n2w + i * EMBED, n2b + i * EMBED,
                                            XWb, EMBED, 1, NTOK);
        gemm_bf16<true><<<dim3(MLPDIM / 128, NTOK / 128), 256, 0, stream>>>(
            XWb, W1, mlp_b1 + i * MLPDIM, MIDB, NTOK, MLPDIM, EMBED);
        gemm_bf16<false><<<dim3(EMBED / 128, NTOK / 128), 256, 0, stream>>>(
            MIDB, W2, mlp_b2 + i * EMBED, PO, NTOK, EMBED, MLPDIM);
        add_inplace<<<(NE + 255) / 256, 256, 0, stream>>>(H, PO, NE);
    }

    // ---- neck ----
    f2b4<<<(NE / 4 + 255) / 256, 256, 0, stream>>>(H, XWb, NE / 4);
    f2b4<<<(OUTC * EMBED / 4 + 255) / 256, 256, 0, stream>>>(neck_w1, WQ, OUTC * EMBED / 4);
    gemm_bf16<false><<<dim3(OUTC / 128, NTOK / 128), 256, 0, stream>>>(
        XWb, WQ, nullptr, PO, NTOK, OUTC, EMBED);
    ln_kernel<<<NTOK, 256, 0, stream>>>(PO, nl1w, nl1b, LNF, OUTC, 0, NTOK);
    im2col3<<<(NTOK * 2304 + 255) / 256, 256, 0, stream>>>(LNF, CONVA, NTOK * 2304);
    f2b4<<<(OUTC * 2304 / 4 + 255) / 256, 256, 0, stream>>>(neck_w2, WP, OUTC * 2304 / 4);
    gemm_bf16<false><<<dim3(OUTC / 128, NTOK / 128), 256, 0, stream>>>(
        CONVA, WP, nullptr, PO, NTOK, OUTC, 2304);
    ln_kernel<<<NTOK, 256, 0, stream>>>(PO, nl2w, nl2b, (float*)d_out, OUTC, 2, NTOK);
}

// Round 3
// 3296.768 us; speedup vs baseline: 3.7477x; 1.7499x over previous
//
#include <hip/hip_runtime.h>
#include <math.h>

#define EMBED   768
#define HEADS   12
#define DEPTH   12
#define TOKS    32
#define NTOK    1024
#define WINSZ   14
#define NWIN    9
#define WTOK    1764        // 9*196
#define WN      196
#define MLPDIM  3072
#define OUTC    256
#define LNEPS   1e-6f

typedef __attribute__((ext_vector_type(8))) short short8;
typedef __attribute__((ext_vector_type(4))) float float4v;

__device__ __forceinline__ unsigned short f2bf(float f) {
    unsigned u = __float_as_uint(f);
    unsigned r = (u + 0x7fffu + ((u >> 16) & 1u)) >> 16;
    return (unsigned short)r;
}
__device__ __forceinline__ float bf2f(unsigned short s) {
    return __uint_as_float((unsigned)s << 16);
}

// ---------------- f32 -> bf16 conversion (4 elems/thread) ------------------
__global__ void f2b4(const float* __restrict__ in, unsigned short* __restrict__ out, int n4) {
    int i = blockIdx.x * blockDim.x + threadIdx.x;
    if (i >= n4) return;
    float4 v = ((const float4*)in)[i];
    ushort4 o;
    o.x = f2bf(v.x); o.y = f2bf(v.y); o.z = f2bf(v.z); o.w = f2bf(v.w);
    ((ushort4*)out)[i] = o;
}

// fused per-layer weight conversion: qkv(2304x768), proj(768x768), mlp1(3072x768), mlp2(768x3072)
__global__ void convw4(const float* __restrict__ a, const float* __restrict__ b,
                       const float* __restrict__ c, const float* __restrict__ d,
                       unsigned short* __restrict__ oa, unsigned short* __restrict__ ob,
                       unsigned short* __restrict__ oc, unsigned short* __restrict__ od) {
    int i = blockIdx.x * blockDim.x + threadIdx.x;   // in float4 units, total 1769472
    const float* s; unsigned short* o; int off;
    if (i < 442368)       { s = a; o = oa; off = i; }
    else if (i < 589824)  { s = b; o = ob; off = i - 442368; }
    else if (i < 1179648) { s = c; o = oc; off = i - 589824; }
    else                  { s = d; o = od; off = i - 1179648; }
    float4 v = ((const float4*)s)[off];
    ushort4 w;
    w.x = f2bf(v.x); w.y = f2bf(v.y); w.z = f2bf(v.z); w.w = f2bf(v.w);
    ((ushort4*)o)[off] = w;
}

// ---------------- bf16 MFMA GEMM: C[M,N] = A[M,K] @ B[N,K]^T + bias --------
// OMODE: 0 = f32 out, 1 = bf16 out, 2 = bf16+GELU out, 3 = qkv split (bf16 Q/K + transposed V)
template<int OMODE>
__global__ __launch_bounds__(256) void gemm_bf16(
        const unsigned short* __restrict__ A, const unsigned short* __restrict__ B,
        const float* __restrict__ bias, void* __restrict__ Cout,
        int M, int N, int K,
        unsigned short* __restrict__ vout, int VN, int VNP) {
    __shared__ unsigned short As[128 * 72];   // [128][64] + pad 8
    __shared__ unsigned short Bs[128 * 72];
    const int tid = threadIdx.x;
    const int lane = tid & 63, wave = tid >> 6;
    const int wm = wave >> 1, wn = wave & 1;
    const int m0 = blockIdx.y * 128, n0 = blockIdx.x * 128;
    float4v acc[4][4];
#pragma unroll
    for (int i = 0; i < 4; i++)
#pragma unroll
        for (int j = 0; j < 4; j++) acc[i][j] = (float4v){0.f, 0.f, 0.f, 0.f};

    const int lrow = tid >> 3;          // 0..31
    const int lcol = (tid & 7) * 8;     // 0..56 (bf16 elems)
    const int q4 = lane >> 4;           // quad id 0..3
    const int l15 = lane & 15;

    for (int k0 = 0; k0 < K; k0 += 64) {
        __syncthreads();
#pragma unroll
        for (int r = 0; r < 4; r++) {
            int row = lrow + r * 32;
            int gm = m0 + row; if (gm >= M) gm = M - 1;
            uint4 va = *(const uint4*)(A + (size_t)gm * K + k0 + lcol);
            *(uint4*)(&As[row * 72 + lcol]) = va;
            int gn = n0 + row;   // N % 128 == 0, always valid
            uint4 vb = *(const uint4*)(B + (size_t)gn * K + k0 + lcol);
            *(uint4*)(&Bs[row * 72 + lcol]) = vb;
        }
        __syncthreads();
#pragma unroll
        for (int kk = 0; kk < 64; kk += 32) {
            short8 af[4], bf[4];
#pragma unroll
            for (int i = 0; i < 4; i++)
                af[i] = *(const short8*)(&As[(wm * 64 + i * 16 + l15) * 72 + kk + q4 * 8]);
#pragma unroll
            for (int j = 0; j < 4; j++)
                bf[j] = *(const short8*)(&Bs[(wn * 64 + j * 16 + l15) * 72 + kk + q4 * 8]);
#pragma unroll
            for (int i = 0; i < 4; i++)
#pragma unroll
                for (int j = 0; j < 4; j++)
                    acc[i][j] = __builtin_amdgcn_mfma_f32_16x16x32_bf16(
                        af[i], bf[j], acc[i][j], 0, 0, 0);
        }
    }
#pragma unroll
    for (int i = 0; i < 4; i++) {
#pragma unroll
        for (int r = 0; r < 4; r++) {
            int m = m0 + wm * 64 + i * 16 + q4 * 4 + r;
            if (m >= M) continue;
            int win = 0, mt = 0;
            if (OMODE == 3) { win = m / VN; mt = m - win * VN; }
#pragma unroll
            for (int j = 0; j < 4; j++) {
                int n = n0 + wn * 64 + j * 16 + l15;
                float v = acc[i][j][r];
                if (bias) v += bias[n];
                if (OMODE == 0) {
                    ((float*)Cout)[(size_t)m * N + n] = v;
                } else if (OMODE == 1) {
                    ((unsigned short*)Cout)[(size_t)m * N + n] = f2bf(v);
                } else if (OMODE == 2) {
                    v = 0.5f * v * (1.f + erff(v * 0.70710678118654752f));
                    ((unsigned short*)Cout)[(size_t)m * N + n] = f2bf(v);
                } else {
                    if (n < 1536) {
                        ((unsigned short*)Cout)[(size_t)m * 2304 + n] = f2bf(v);
                    } else {
                        int nn = n - 1536;
                        int head = nn >> 6, dd = nn & 63;
                        vout[(size_t)((win * HEADS + head) * 64 + dd) * VNP + mt] = f2bf(v);
                    }
                }
            }
        }
    }
}

// ---------------- fused MFMA flash attention ------------------------------
// qkv bf16 [tok][2304] (Q at 0, K at 768; V lives transposed in vt).
// vt bf16 [bh][64 d][VNP tok]. out bf16 [tok][768].
// Block: (q-tile of 64 rows) x (bh). 4 waves, wave w owns q rows w*16..w*16+15.
template<int N, int HH, int WW, int VNP>
__global__ __launch_bounds__(256) void attn_mfma(
        const unsigned short* __restrict__ qkv, const unsigned short* __restrict__ vt,
        const float* __restrict__ rel_h, const float* __restrict__ rel_w,
        unsigned short* __restrict__ out) {
    constexpr int NT = (N + 63) / 64;
    __shared__ unsigned short Qs[64 * 72];
    __shared__ unsigned short Pw[4][16 * 72];
    __shared__ float bhs[64][HH];
    __shared__ float bws[64][WW];
    const int tid = threadIdx.x, lane = tid & 63, w = tid >> 6;
    const int l15 = lane & 15, q4 = lane >> 4;
    const int bh = blockIdx.y, winI = bh / HEADS, head = bh % HEADS;
    const int base = winI * N;
    const int q0 = blockIdx.x * 64;

    // ---- stage Q tile (64 x 64 bf16) into LDS for bias dots ----
    {
        int row = tid >> 3, c8 = (tid & 7) * 8;
#pragma unroll
        for (int it = 0; it < 2; it++) {
            int rr = row + it * 32;
            int qr = q0 + rr; if (qr >= N) qr = N - 1;
            uint4 v = *(const uint4*)(qkv + (size_t)(base + qr) * 2304 + head * 64 + c8);
            *(uint4*)(&Qs[rr * 72 + c8]) = v;
        }
    }
    __syncthreads();
    // ---- decomposed rel-pos bias tables ----
    for (int idx = tid; idx < 64 * (HH + WW); idx += 256) {
        int ql = idx / (HH + WW), t = idx - ql * (HH + WW);
        int qg = q0 + ql;
        int qh = qg / WW, qw = qg - qh * WW;
        const float* rp = (t < HH) ? rel_h + (size_t)(qh - t + HH - 1) * 64
                                   : rel_w + (size_t)(qw - (t - HH) + WW - 1) * 64;
        float s = 0.f;
#pragma unroll 8
        for (int d = 0; d < 64; d++) s += bf2f(Qs[ql * 72 + d]) * rp[d];
        if (t < HH) bhs[ql][t] = s; else bws[ql][t - HH] = s;
    }
    __syncthreads();

    // ---- per-wave Q fragments (reused across all K tiles) ----
    short8 aq0, aq1;
    {
        int qr = q0 + w * 16 + l15; if (qr >= N) qr = N - 1;
        const unsigned short* qp = qkv + (size_t)(base + qr) * 2304 + head * 64;
        aq0 = *(const short8*)(qp + q4 * 8);
        aq1 = *(const short8*)(qp + 32 + q4 * 8);
    }
    float m_r[4], l_r[4];
    float4v acc_o[4];
#pragma unroll
    for (int r = 0; r < 4; r++) { m_r[r] = -1e30f; l_r[r] = 0.f; }
#pragma unroll
    for (int s = 0; s < 4; s++) acc_o[s] = (float4v){0.f, 0.f, 0.f, 0.f};

    const unsigned short* vbase = vt + (size_t)bh * 64 * VNP;

#pragma unroll 1
    for (int kt = 0; kt < NT; kt++) {
        // ---- scores: 4 n-subtiles of 16 cols ----
        float sv[4][4];   // [s][r]
#pragma unroll
        for (int s = 0; s < 4; s++) {
            int kr = kt * 64 + s * 16 + l15; if (kr >= N) kr = N - 1;
            const unsigned short* kp = qkv + (size_t)(base + kr) * 2304 + 768 + head * 64;
            short8 kb0 = *(const short8*)(kp + q4 * 8);
            short8 kb1 = *(const short8*)(kp + 32 + q4 * 8);
            float4v sf = (float4v){0.f, 0.f, 0.f, 0.f};
            sf = __builtin_amdgcn_mfma_f32_16x16x32_bf16(aq0, kb0, sf, 0, 0, 0);
            sf = __builtin_amdgcn_mfma_f32_16x16x32_bf16(aq1, kb1, sf, 0, 0, 0);
            int col = kt * 64 + s * 16 + l15;
            if (col < N) {
                int kh = col / WW, kw = col - kh * WW;
#pragma unroll
                for (int r = 0; r < 4; r++) {
                    int ql = w * 16 + q4 * 4 + r;
                    sv[s][r] = sf[r] * 0.125f + bhs[ql][kh] + bws[ql][kw];
                }
            } else {
#pragma unroll
                for (int r = 0; r < 4; r++) sv[s][r] = -1e30f;
            }
        }
        // ---- online softmax update (per q row, reduce across 16 l15 lanes) ----
        float p[4][4];
#pragma unroll
        for (int r = 0; r < 4; r++) {
            float t = fmaxf(fmaxf(sv[0][r], sv[1][r]), fmaxf(sv[2][r], sv[3][r]));
#pragma unroll
            for (int off = 1; off < 16; off <<= 1) t = fmaxf(t, __shfl_xor(t, off));
            float mn = fmaxf(m_r[r], t);
            float alpha = __expf(m_r[r] - mn);
            m_r[r] = mn;
            float ps = 0.f;
#pragma unroll
            for (int s = 0; s < 4; s++) { p[s][r] = __expf(sv[s][r] - mn); ps += p[s][r]; }
#pragma unroll
            for (int off = 1; off < 16; off <<= 1) ps += __shfl_xor(ps, off);
            l_r[r] = l_r[r] * alpha + ps;
#pragma unroll
            for (int s = 0; s < 4; s++) acc_o[s][r] *= alpha;
        }
        // ---- P -> LDS (C-layout -> A-layout round trip, wave-private) ----
#pragma unroll
        for (int s = 0; s < 4; s++)
#pragma unroll
            for (int r = 0; r < 4; r++)
                Pw[w][(q4 * 4 + r) * 72 + s * 16 + l15] = f2bf(p[s][r]);
        short8 af0 = *(const short8*)(&Pw[w][l15 * 72 + q4 * 8]);
        short8 af1 = *(const short8*)(&Pw[w][l15 * 72 + 32 + q4 * 8]);
        // ---- PV: O[16 q][64 d] += P(16x64) * V(64x64) ----
        const unsigned short* vb = vbase + kt * 64;
#pragma unroll
        for (int s2 = 0; s2 < 4; s2++) {
            const unsigned short* vr = vb + (size_t)(s2 * 16 + l15) * VNP;
            short8 b0 = *(const short8*)(vr + q4 * 8);
            short8 b1 = *(const short8*)(vr + 32 + q4 * 8);
            acc_o[s2] = __builtin_amdgcn_mfma_f32_16x16x32_bf16(af0, b0, acc_o[s2], 0, 0, 0);
            acc_o[s2] = __builtin_amdgcn_mfma_f32_16x16x32_bf16(af1, b1, acc_o[s2], 0, 0, 0);
        }
    }
    // ---- store ----
#pragma unroll
    for (int r = 0; r < 4; r++) {
        int qg = q0 + w * 16 + q4 * 4 + r;
        if (qg >= N) continue;
        float inv = 1.f / l_r[r];
#pragma unroll
        for (int s2 = 0; s2 < 4; s2++)
            out[(size_t)(base + qg) * EMBED + head * 64 + s2 * 16 + l15] =
                f2bf(acc_o[s2][r] * inv);
    }
}

// ---------------- LayerNorm over last dim ----------------------------------
// mode 0: f32 out [M,C]; mode 1: bf16 out [M,C]; mode 2: f32 out transposed [C,M]
__global__ __launch_bounds__(256) void ln_kernel(
        const float* __restrict__ in, const float* __restrict__ w,
        const float* __restrict__ b, void* __restrict__ out,
        int C, int mode, int M) {
    int row = blockIdx.x;
    const float* x = in + (size_t)row * C;
    float s1 = 0.f, s2 = 0.f;
    for (int c = threadIdx.x; c < C; c += blockDim.x) {
        float v = x[c]; s1 += v; s2 += v * v;
    }
    for (int off = 32; off; off >>= 1) {
        s1 += __shfl_down(s1, off);
        s2 += __shfl_down(s2, off);
    }
    __shared__ float sh1[4], sh2[4];
    __shared__ float mu, rstd;
    int wave = threadIdx.x >> 6, lane = threadIdx.x & 63;
    if (lane == 0) { sh1[wave] = s1; sh2[wave] = s2; }
    __syncthreads();
    if (threadIdx.x == 0) {
        float t1 = 0.f, t2 = 0.f;
        for (int i = 0; i < 4; i++) { t1 += sh1[i]; t2 += sh2[i]; }
        float m = t1 / C;
        mu = m; rstd = rsqrtf(t2 / C - m * m + LNEPS);
    }
    __syncthreads();
    float m = mu, r = rstd;
    for (int c = threadIdx.x; c < C; c += blockDim.x) {
        float v = (x[c] - m) * r * w[c] + b[c];
        if (mode == 0)      ((float*)out)[(size_t)row * C + c] = v;
        else if (mode == 1) ((unsigned short*)out)[(size_t)row * C + c] = f2bf(v);
        else                ((float*)out)[(size_t)c * M + row] = v;
    }
}

// ---------------- window partition / unpartition ---------------------------
__global__ __launch_bounds__(256) void win_partition(
        const float* __restrict__ in, unsigned short* __restrict__ out) {
    int t = blockIdx.x;                    // 0..1763
    int w = t / WN, r = t % WN;
    int wy = r / WINSZ, wx = r % WINSZ;
    int gy = (w / 3) * WINSZ + wy, gx = (w % 3) * WINSZ + wx;
    bool valid = (gy < TOKS && gx < TOKS);
    const float* src = in + (size_t)(gy * TOKS + gx) * EMBED;
    unsigned short* dst = out + (size_t)t * EMBED;
    for (int c = threadIdx.x; c < EMBED; c += blockDim.x)
        dst[c] = valid ? f2bf(src[c]) : 0;
}

__global__ __launch_bounds__(256) void win_unpartition_add(
        const float* __restrict__ winb, float* __restrict__ h) {
    int p = blockIdx.x;                    // 0..1023
    int gy = p / TOKS, gx = p % TOKS;
    int w = (gy / WINSZ) * 3 + gx / WINSZ;
    int t = w * WN + (gy % WINSZ) * WINSZ + (gx % WINSZ);
    const float* src = winb + (size_t)t * EMBED;
    float* dst = h + (size_t)p * EMBED;
    for (int c = threadIdx.x; c < EMBED; c += blockDim.x) dst[c] += src[c];
}

// ---------------- elementwise ----------------------------------------------
__global__ void add_inplace(float* __restrict__ a, const float* __restrict__ b, int n) {
    int i = blockIdx.x * blockDim.x + threadIdx.x;
    if (i < n) a[i] += b[i];
}
__global__ void add_bias_pos(float* __restrict__ h, const float* __restrict__ pb,
                             const float* __restrict__ pos, int n) {
    int i = blockIdx.x * blockDim.x + threadIdx.x;
    if (i < n) h[i] += pb[i % EMBED] + pos[i];
}

// ---------------- patch-embed im2col (bf16 out) ----------------------------
__global__ void im2col_patch(const float* __restrict__ x, unsigned short* __restrict__ A, int n) {
    int i = blockIdx.x * blockDim.x + threadIdx.x;
    if (i >= n) return;
    int t = i / EMBED, kidx = i % EMBED;
    int c = kidx >> 8, r = kidx & 255;
    int ph = r >> 4, pw = r & 15;
    int ty = t >> 5, tx = t & 31;
    A[i] = f2bf(x[(size_t)c * 512 * 512 + (size_t)(ty * 16 + ph) * 512 + (tx * 16 + pw)]);
}

// ---------------- neck 3x3 conv im2col (bf16 out) --------------------------
__global__ void im2col3(const float* __restrict__ in, unsigned short* __restrict__ out, int n) {
    int i = blockIdx.x * blockDim.x + threadIdx.x;
    if (i >= n) return;
    int p = i / 2304, k = i % 2304;
    int c = k / 9, r9 = k % 9;
    int ky = r9 / 3, kx = r9 % 3;
    int py = p >> 5, px = p & 31;
    int ny = py + ky - 1, nx = px + kx - 1;
    float v = (ny >= 0 && ny < TOKS && nx >= 0 && nx < TOKS)
                ? in[(size_t)(ny * TOKS + nx) * OUTC + c] : 0.f;
    out[i] = f2bf(v);
}

// ---------------- host orchestration ---------------------------------------
extern "C" void kernel_launch(void* const* d_in, const int* in_sizes, int n_in,
                              void* d_out, int out_size, void* d_ws, size_t ws_size,
                              hipStream_t stream) {
    const float* x        = (const float*)d_in[0];
    const float* patch_w  = (const float*)d_in[1];
    const float* patch_b  = (const float*)d_in[2];
    const float* pos      = (const float*)d_in[3];
    const float* qkv_w    = (const float*)d_in[4];
    const float* qkv_b    = (const float*)d_in[5];
    const float* proj_w   = (const float*)d_in[6];
    const float* proj_b   = (const float*)d_in[7];
    const float* n1w      = (const float*)d_in[8];
    const float* n1b      = (const float*)d_in[9];
    const float* n2w      = (const float*)d_in[10];
    const float* n2b      = (const float*)d_in[11];
    const float* mlp_w1   = (const float*)d_in[12];
    const float* mlp_b1   = (const float*)d_in[13];
    const float* mlp_w2   = (const float*)d_in[14];
    const float* mlp_b2   = (const float*)d_in[15];
    const float* rhw      = (const float*)d_in[16];
    const float* rww      = (const float*)d_in[17];
    const float* rhg      = (const float*)d_in[18];
    const float* rwg      = (const float*)d_in[19];
    const float* neck_w1  = (const float*)d_in[20];
    const float* nl1w     = (const float*)d_in[21];
    const float* nl1b     = (const float*)d_in[22];
    const float* neck_w2  = (const float*)d_in[23];
    const float* nl2w     = (const float*)d_in[24];
    const float* nl2b     = (const float*)d_in[25];

    char* p = (char*)d_ws;
    float* H    = (float*)p;            p += (size_t)NTOK * EMBED * 4;       // 3.0 MB
    unsigned short* QKVb = (unsigned short*)p; p += (size_t)WTOK * 2304 * 2; // 8.1 MB
    unsigned short* Vt   = (unsigned short*)p; p += (size_t)NWIN * HEADS * 64 * 208 * 2 + 4096; // 2.9 MB
    float* PO   = (float*)p;            p += (size_t)WTOK * EMBED * 4;       // 5.4 MB
    float* LNF  = (float*)p;            p += (size_t)NTOK * EMBED * 4;       // 3.0 MB
    unsigned short* XWb = (unsigned short*)p;  p += (size_t)WTOK * EMBED * 2;
    unsigned short* AOb = (unsigned short*)p;  p += (size_t)WTOK * EMBED * 2;
    unsigned short* WQ  = (unsigned short*)p;  p += (size_t)2304 * 768 * 2;
    unsigned short* WP  = (unsigned short*)p;  p += (size_t)768 * 768 * 2;
    unsigned short* W1  = (unsigned short*)p;  p += (size_t)3072 * 768 * 2;
    unsigned short* W2  = (unsigned short*)p;  p += (size_t)768 * 3072 * 2;
    unsigned short* MIDB  = QKVb;   // alias: MLP mid 1024x3072 bf16
    unsigned short* CONVA = QKVb;   // alias: neck im2col 1024x2304 bf16

    const int NE = NTOK * EMBED;    // 786432

    // ---- patch embed ----
    im2col_patch<<<(NE + 255) / 256, 256, 0, stream>>>(x, XWb, NE);
    f2b4<<<(EMBED * EMBED / 4 + 255) / 256, 256, 0, stream>>>(patch_w, WQ, EMBED * EMBED / 4);
    gemm_bf16<0><<<dim3(EMBED / 128, NTOK / 128), 256, 0, stream>>>(
        XWb, WQ, nullptr, H, NTOK, EMBED, EMBED, nullptr, 0, 0);
    add_bias_pos<<<(NE + 255) / 256, 256, 0, stream>>>(H, patch_b, pos, NE);

    for (int i = 0; i < DEPTH; i++) {
        bool glob = (i == 2 || i == 5 || i == 8 || i == 11);
        convw4<<<(1769472 + 255) / 256, 256, 0, stream>>>(
            qkv_w + (size_t)i * 2304 * 768, proj_w + (size_t)i * 768 * 768,
            mlp_w1 + (size_t)i * 3072 * 768, mlp_w2 + (size_t)i * 768 * 3072,
            WQ, WP, W1, W2);

        if (!glob) {
            ln_kernel<<<NTOK, 256, 0, stream>>>(H, n1w + i * EMBED, n1b + i * EMBED,
                                                LNF, EMBED, 0, NTOK);
            win_partition<<<WTOK, 256, 0, stream>>>(LNF, XWb);
            gemm_bf16<3><<<dim3(2304 / 128, (WTOK + 127) / 128), 256, 0, stream>>>(
                XWb, WQ, qkv_b + i * 2304, QKVb, WTOK, 2304, EMBED, Vt, WN, 208);
            attn_mfma<WN, WINSZ, WINSZ, 208><<<dim3(4, NWIN * HEADS), 256, 0, stream>>>(
                QKVb, Vt, rhw + (size_t)i * 27 * 64, rww + (size_t)i * 27 * 64, AOb);
            gemm_bf16<0><<<dim3(EMBED / 128, (WTOK + 127) / 128), 256, 0, stream>>>(
                AOb, WP, proj_b + i * EMBED, PO, WTOK, EMBED, EMBED, nullptr, 0, 0);
            win_unpartition_add<<<NTOK, 256, 0, stream>>>(PO, H);
        } else {
            ln_kernel<<<NTOK, 256, 0, stream>>>(H, n1w + i * EMBED, n1b + i * EMBED,
                                                XWb, EMBED, 1, NTOK);
            gemm_bf16<3><<<dim3(2304 / 128, NTOK / 128), 256, 0, stream>>>(
                XWb, WQ, qkv_b + i * 2304, QKVb, NTOK, 2304, EMBED, Vt, NTOK, NTOK);
            attn_mfma<NTOK, TOKS, TOKS, NTOK><<<dim3(16, HEADS), 256, 0, stream>>>(
                QKVb, Vt, rhg + (size_t)i * 63 * 64, rwg + (size_t)i * 63 * 64, AOb);
            gemm_bf16<0><<<dim3(EMBED / 128, NTOK / 128), 256, 0, stream>>>(
                AOb, WP, proj_b + i * EMBED, PO, NTOK, EMBED, EMBED, nullptr, 0, 0);
            add_inplace<<<(NE + 255) / 256, 256, 0, stream>>>(H, PO, NE);
        }
        // MLP
        ln_kernel<<<NTOK, 256, 0, stream>>>(H, n2w + i * EMBED, n2b + i * EMBED,
                                            XWb, EMBED, 1, NTOK);
        gemm_bf16<2><<<dim3(MLPDIM / 128, NTOK / 128), 256, 0, stream>>>(
            XWb, W1, mlp_b1 + i * MLPDIM, MIDB, NTOK, MLPDIM, EMBED, nullptr, 0, 0);
        gemm_bf16<0><<<dim3(EMBED / 128, NTOK / 128), 256, 0, stream>>>(
            MIDB, W2, mlp_b2 + i * EMBED, PO, NTOK, EMBED, MLPDIM, nullptr, 0, 0);
        add_inplace<<<(NE + 255) / 256, 256, 0, stream>>>(H, PO, NE);
    }

    // ---- neck ----
    f2b4<<<(NE / 4 + 255) / 256, 256, 0, stream>>>(H, XWb, NE / 4);
    f2b4<<<(OUTC * EMBED / 4 + 255) / 256, 256, 0, stream>>>(neck_w1, WQ, OUTC * EMBED / 4);
    gemm_bf16<0><<<dim3(OUTC / 128, NTOK / 128), 256, 0, stream>>>(
        XWb, WQ, nullptr, PO, NTOK, OUTC, EMBED, nullptr, 0, 0);
    ln_kernel<<<NTOK, 256, 0, stream>>>(PO, nl1w, nl1b, LNF, OUTC, 0, NTOK);
    im2col3<<<(NTOK * 2304 + 255) / 256, 256, 0, stream>>>(LNF, CONVA, NTOK * 2304);
    f2b4<<<(OUTC * 2304 / 4 + 255) / 256, 256, 0, stream>>>(neck_w2, WP, OUTC * 2304 / 4);
    gemm_bf16<0><<<dim3(OUTC / 128, NTOK / 128), 256, 0, stream>>>(
        CONVA, WP, nullptr, PO, NTOK, OUTC, 2304, nullptr, 0, 0);
    ln_kernel<<<NTOK, 256, 0, stream>>>(PO, nl2w, nl2b, (float*)d_out, OUTC, 2, NTOK);
}